// Round 11
// baseline (307.673 us; speedup 1.0000x reference)
//
#include <hip/hip_runtime.h>
#include <hip/hip_bf16.h>

// AdaptiveReLULayer: out[b,n,o] = leaky( sum_i x[b,n,i] * weight[idx[b],i,o] + bias[o], 0.2 )
// B=2048, N=256, IN=256, OUT=256, C=1024.  f32 I/O; bf16 MFMA, f32 accum.
//
// R13 vs R11 (248us best) / R12 (292us, FAILED: 128-row tile re-amplified
// WRITE +189MB and pushed w out of L3, single-buffer B exposed its flush):
// R11 accounting: block lifetime ~15.5us vs ~4us intrinsic path; HBM activity
// (x at birth, out at death) occupies ~25% of a block's life; with 2 resident
// blocks/CU the CU's HBM duty cycle ~50% -> 4.3 of 6.3 TB/s.  R13 pulls the
// one unpulled lever at this operating point: MORE STAGGERED BLOCKS PER CU.
//   * tile 32 rows x 256 o (A panel 16KB bf16); LDS = 16 + 2x16 = 48KB
//     -> 3 blocks/CU.  grid = 2048*8; XCD swizzle keeps a batch's 8 n-tiles
//     adjacent -> one 256KB w panel serves 8 co-resident blocks per XCD L2
//     (working set ~3MB < 4MB).
//   * everything else R11 VERBATIM: 256-col tiles (x HBM 1x, WRITE clean
//     524MB), bbyte zero-conflict B layout, same B staging thread-map,
//     depth-2 named reg sets + sched_barrier anti-sinking, one lgkm+barrier
//     per round, nt x-loads / out-stores, plain (cacheable) w loads.
// Pre-committed: VGPR ~105-125 (rb must hold); WRITE must stay ~524MB;
// predict 205-220us if duty-cycle theory holds, flat if exhausted.

#define BK 32

typedef __attribute__((ext_vector_type(8))) __bf16 bf16x8;
typedef __attribute__((ext_vector_type(4))) float f32x4;
typedef __attribute__((ext_vector_type(4))) unsigned int u32x4;
typedef __attribute__((ext_vector_type(2))) unsigned int u32x2;

#define B_LDS 16384   // B^T dbuf base (A panel occupies 0..16383)

__device__ __forceinline__ f32x4 MFMA(u32x4 a, u32x4 b, f32x4 c) {
    return __builtin_amdgcn_mfma_f32_16x16x32_bf16(
        __builtin_bit_cast(bf16x8, a), __builtin_bit_cast(bf16x8, b), c, 0, 0, 0);
}

__device__ __forceinline__ unsigned pk2(float a, float b) {
    __hip_bfloat16 ha = __float2bfloat16(a);
    __hip_bfloat16 hb = __float2bfloat16(b);
    unsigned short sa, sb;
    __builtin_memcpy(&sa, &ha, 2);
    __builtin_memcpy(&sb, &hb, 2);
    return (unsigned)sa | ((unsigned)sb << 16);
}

// B^T tile byte offset for (o 0..255, p 0..31): 128 row-pairs x 128B.
// R7/R11-measured ZERO bank conflicts for this read/write shape.
__device__ __forceinline__ int bbyte(int o, int p) {
    const int rp  = o >> 1;
    const int raw = ((o & 1) << 2) | (p >> 3);
    const int key = (rp ^ (o >> 4)) & 7;
    return rp * 128 + ((raw ^ key) << 4) + ((p & 7) << 1);
}

__global__ __launch_bounds__(256, 3) void argemm_kernel(
    const float* __restrict__ x,
    const int* __restrict__ idx,
    const float* __restrict__ w,
    const float* __restrict__ bias,
    float* __restrict__ out)
{
    __shared__ __align__(16) char lds[49152];  // A panel 16KB | B^T dbuf 2x16KB

    const int tid = threadIdx.x;
    const int l   = tid & 63;
    const int wid = tid >> 6;
    const int wr  = wid >> 1;   // 16-row half of the 32-row tile
    const int wc  = wid & 1;    // 128-col half of the 256-col tile

    // XCD-chunked swizzle: the 8 n-tiles of one b are logically adjacent ->
    // same XCD, co-temporal -> one w panel pull serves all 8 from L2.
    const unsigned bid     = blockIdx.x;
    const unsigned chunk   = gridDim.x >> 3;
    const unsigned logical = (bid & 7u) * chunk + (bid >> 3);
    const int b  = (int)(logical >> 3);
    const int n0 = (int)(logical & 7u) * 32;

    const int g = l >> 4;   // 0..3 (k-subgroup)
    const int i = l & 15;   // 0..15

    const int c = idx[b];
    const float* xb = x + (size_t)b * (256 * 256);
    const float* wb = w + (size_t)c * (256 * 256);

    // ---- B staging maps (R11 verbatim) ----
    const int q   = tid & 63;        // o-quad: cols q*4 .. q*4+3
    const int oct = tid >> 6;        // p-octet: p = oct*8 .. oct*8+7
    const float* wp = wb + (size_t)(oct * 8) * 256 + q * 4;
    int bW[4];
#pragma unroll
    for (int j = 0; j < 4; ++j)
        bW[j] = bbyte(q * 4 + j, oct * 8);

    // ---- fragment read addresses ----
    int bR[8];
#pragma unroll
    for (int n = 0; n < 8; ++n)
        bR[n] = bbyte(wc * 128 + n * 16 + i, g * 8);
    const int aRow = (wr * 16 + i) * 512;
    const int aKey = (wr * 16 + i) & 31;

    // ---- two named B staging sets: tile T -> set T&1 ----
    f32x4 rb[2][8];   // [set][e]: k-row = T*32 + oct*8 + e

    auto issueB = [&](int t, int s) {
#pragma unroll
        for (int e = 0; e < 8; ++e)
            rb[s][e] = *(const f32x4*)(wp + (size_t)(t * BK + e) * 256);
    };
    auto flushB = [&](int T, int s) {
        char* base = (char*)lds + B_LDS + (T & 1) * 16384;
#pragma unroll
        for (int j = 0; j < 4; ++j) {
            u32x4 pq;                                   // 8 bf16, p ascending
            pq.x = pk2(rb[s][0][j], rb[s][1][j]);
            pq.y = pk2(rb[s][2][j], rb[s][3][j]);
            pq.z = pk2(rb[s][4][j], rb[s][5][j]);
            pq.w = pk2(rb[s][6][j], rb[s][7][j]);
            *(u32x4*)(base + bW[j]) = pq;
        }
    };

    // ---- prologue: B tiles 0,1 in flight; A panel staged (nt, sequential) ----
    issueB(0, 0);
    __builtin_amdgcn_sched_barrier(0);
    issueB(1, 1);
    __builtin_amdgcn_sched_barrier(0);

    // A: wave stages rows wid*8 .. wid*8+7, one full 1KB row per instruction.
    {
        const float* xw = xb + (n0 + wid * 8) * 256 + l * 4;
        const int csw = l >> 1;
        const int sub = (l & 1) * 8;
        f32x4 xa[8];
#pragma unroll
        for (int j = 0; j < 8; ++j)
            xa[j] = __builtin_nontemporal_load((const f32x4*)(xw + j * 256));
        __builtin_amdgcn_sched_barrier(0);
#pragma unroll
        for (int j = 0; j < 8; ++j) {
            const int r = wid * 8 + j;
            u32x2 p;
            p.x = pk2(xa[j].x, xa[j].y);
            p.y = pk2(xa[j].z, xa[j].w);
            *(u32x2*)((char*)lds + r * 512 + ((csw ^ (r & 31)) << 4) + sub) = p;
        }
    }

    flushB(0, 0);
    issueB(2, 0);
    __builtin_amdgcn_sched_barrier(0);
    asm volatile("s_waitcnt lgkmcnt(0)" ::: "memory");
    __builtin_amdgcn_sched_barrier(0);
    __builtin_amdgcn_s_barrier();

    f32x4 acc[8];
#pragma unroll
    for (int n = 0; n < 8; ++n)
        acc[n] = (f32x4){0.f, 0.f, 0.f, 0.f};

    // ---- K loop: 8 rounds (R11 skeleton) ----
#pragma unroll
    for (int t = 0; t < 8; ++t) {
        const char* bbuf = (const char*)lds + B_LDS + (t & 1) * 16384;

        const u32x4 af = *(const u32x4*)((const char*)lds + aRow
                                         + (((t * 4 + g) ^ aKey) << 4));
#pragma unroll
        for (int n = 0; n < 8; ++n) {
            const u32x4 bq = *(const u32x4*)(bbuf + bR[n]);
            acc[n] = MFMA(af, bq, acc[n]);
        }

        if (t < 7) {
            flushB(t + 1, (t + 1) & 1);   // loads issued 2 rounds ago
            if (t < 5) {
                issueB(t + 3, (t + 1) & 1);
                __builtin_amdgcn_sched_barrier(0);   // forbid load sinking
            }
            asm volatile("s_waitcnt lgkmcnt(0)" ::: "memory");
            __builtin_amdgcn_sched_barrier(0);
            __builtin_amdgcn_s_barrier();
        }
    }

    // ---- epilogue: bias + LeakyReLU(0.2), nontemporal f32 store ----
    float biasf[8];
#pragma unroll
    for (int n = 0; n < 8; ++n)
        biasf[n] = bias[wc * 128 + n * 16 + i];

    float* ob = out + (size_t)b * (256 * 256);
#pragma unroll
    for (int r = 0; r < 4; ++r) {
        const int row = n0 + wr * 16 + g * 4 + r;
#pragma unroll
        for (int n = 0; n < 8; ++n) {
            float v = acc[n][r] + biasf[n];
            v = (v >= 0.f) ? v : 0.2f * v;
            __builtin_nontemporal_store(v, &ob[row * 256 + wc * 128 + n * 16 + i]);
        }
    }
}

extern "C" void kernel_launch(void* const* d_in, const int* in_sizes, int n_in,
                              void* d_out, int out_size, void* d_ws, size_t ws_size,
                              hipStream_t stream) {
    const float* x    = (const float*)d_in[0];
    const int*   idx  = (const int*)d_in[1];
    const float* w    = (const float*)d_in[2];
    const float* bias = (const float*)d_in[3];
    float*       out  = (float*)d_out;
    (void)d_ws; (void)ws_size; (void)n_in; (void)out_size;

    const int B = in_sizes[1];          // 2048
    dim3 grid((unsigned)(B * 8)), block(256);
    hipLaunchKernelGGL(argemm_kernel, grid, block, 0, stream, x, idx, w, bias, out);
}

// Round 12
// 272.116 us; speedup vs baseline: 1.1307x; 1.1307x over previous
//
#include <hip/hip_runtime.h>
#include <hip/hip_bf16.h>

// AdaptiveReLULayer: out[b,n,o] = leaky( sum_i x[b,n,i] * weight[idx[b],i,o] + bias[o], 0.2 )
// B=2048, N=256, IN=256, OUT=256, C=1024.  f32 I/O; bf16 MFMA, f32 accum.
//
// R14 vs R11 (248us best): clean retest of the w-fabric theory.  R11 moves
// 2.1GB of w over CU<-L2 (8192 blocks x 256KB) vs 1.07GB HBM -- two
// comparable co-binders.  Both prior fabric tests were VOID: R9 (conflicts +
// no-nt), R12 (launch_bounds(512,4) capped VGPR at 128 -> rb collapsed,
// VGPR=64; plus non-64-row store ghost).  R14 halves fabric with every
// R11-proven element kept and the collapse trap removed:
//   * tile 128 rows x 256 o, 512 threads / 8 waves, grid = 2048*2 = 4096.
//     Per-wave mix identical to R11 (af[2] + 8 bq + 16 MFMA per round);
//     per-thread rb halves to rb[2][4] (32 regs).  NO min-waves bound.
//   * B staging: same 64-o-quads-per-wave measured-zero bbyte write shape
//     (u32x2 halves of each 16B chunk), depth-2 named sets + anti-sinking.
//   * LDS = A panel 64KB + B dbuf 32KB = 96KB -> 1 block/CU, 8 waves/CU
//     (same wave count as R11's 2x4).
//   * w fabric 4096 x 256KB = 1.07GB (2x cut); XCD swizzle keeps b-twins
//     adjacent -> w L2-coincident.  nt x-loads / out-stores kept.
// Pre-committed: VGPR 130-170 (<=100 void); WRITE ~524MB (>560 = store
// ghost -> revert); predict 210-235us if fabric co-binds, flat if not.

#define BK 32

typedef __attribute__((ext_vector_type(8))) __bf16 bf16x8;
typedef __attribute__((ext_vector_type(4))) float f32x4;
typedef __attribute__((ext_vector_type(4))) unsigned int u32x4;
typedef __attribute__((ext_vector_type(2))) unsigned int u32x2;

#define B_LDS 65536   // B^T dbuf base (A panel occupies 0..65535)

__device__ __forceinline__ f32x4 MFMA(u32x4 a, u32x4 b, f32x4 c) {
    return __builtin_amdgcn_mfma_f32_16x16x32_bf16(
        __builtin_bit_cast(bf16x8, a), __builtin_bit_cast(bf16x8, b), c, 0, 0, 0);
}

__device__ __forceinline__ unsigned pk2(float a, float b) {
    __hip_bfloat16 ha = __float2bfloat16(a);
    __hip_bfloat16 hb = __float2bfloat16(b);
    unsigned short sa, sb;
    __builtin_memcpy(&sa, &ha, 2);
    __builtin_memcpy(&sb, &hb, 2);
    return (unsigned)sa | ((unsigned)sb << 16);
}

// B^T tile byte offset for (o 0..255, p 0..31): 128 row-pairs x 128B.
// R7/R11-measured ZERO bank conflicts for these read/write shapes.
__device__ __forceinline__ int bbyte(int o, int p) {
    const int rp  = o >> 1;
    const int raw = ((o & 1) << 2) | (p >> 3);
    const int key = (rp ^ (o >> 4)) & 7;
    return rp * 128 + ((raw ^ key) << 4) + ((p & 7) << 1);
}

__global__ __launch_bounds__(512) void argemm_kernel(
    const float* __restrict__ x,
    const int* __restrict__ idx,
    const float* __restrict__ w,
    const float* __restrict__ bias,
    float* __restrict__ out)
{
    __shared__ __align__(16) char lds[98304];  // A panel 64KB | B^T dbuf 2x16KB

    const int tid = threadIdx.x;
    const int l   = tid & 63;
    const int wid = tid >> 6;   // 0..7
    const int wr  = wid >> 1;   // 32-row quarter of the 128-row tile
    const int wc  = wid & 1;    // 128-col half

    // XCD-chunked swizzle: the two 128-row tiles of one b are adjacent ->
    // same XCD, co-temporal -> w panel L2-coincident.
    const unsigned bid     = blockIdx.x;
    const unsigned chunk   = gridDim.x >> 3;
    const unsigned logical = (bid & 7u) * chunk + (bid >> 3);
    const int b  = (int)(logical >> 1);
    const int n0 = (int)(logical & 1u) * 128;

    const int g = l >> 4;   // 0..3 (k-subgroup)
    const int i = l & 15;   // 0..15

    const int c = idx[b];
    const float* xb = x + (size_t)b * (256 * 256);
    const float* wb = w + (size_t)c * (256 * 256);

    // ---- B staging maps: o-quad q (0..63), slot sl -> (p-octet, k-half) ----
    const int q    = tid & 63;
    const int sl   = tid >> 6;        // 0..7
    const int oct  = sl & 3;          // p-octet: p = oct*8 .. +7
    const int half = sl >> 2;         // k-half within octet (0: e 0..3, 1: e 4..7)
    const float* wp = wb + (size_t)(oct * 8 + half * 4) * 256 + q * 4;
    int bW[4];
#pragma unroll
    for (int j = 0; j < 4; ++j)
        bW[j] = bbyte(q * 4 + j, oct * 8) + half * 8;

    // ---- fragment read addresses (R11 shapes) ----
    int bR[8];
#pragma unroll
    for (int n = 0; n < 8; ++n)
        bR[n] = bbyte(wc * 128 + n * 16 + i, g * 8);
    int aRow[2], aKey[2];
#pragma unroll
    for (int m = 0; m < 2; ++m) {
        const int r = wr * 32 + m * 16 + i;
        aRow[m] = r * 512;
        aKey[m] = r & 31;
    }

    // ---- two named B staging sets: tile T -> set T&1 ----
    f32x4 rb[2][4];   // [set][e]: k-row = T*32 + oct*8 + half*4 + e

    auto issueB = [&](int t, int s) {
#pragma unroll
        for (int e = 0; e < 4; ++e)
            rb[s][e] = *(const f32x4*)(wp + (size_t)(t * BK + e) * 256);
    };
    auto flushB = [&](int T, int s) {
        char* base = (char*)lds + B_LDS + (T & 1) * 16384;
#pragma unroll
        for (int j = 0; j < 4; ++j) {
            u32x2 pq;                                   // 4 bf16, p ascending
            pq.x = pk2(rb[s][0][j], rb[s][1][j]);
            pq.y = pk2(rb[s][2][j], rb[s][3][j]);
            *(u32x2*)(base + bW[j]) = pq;
        }
    };

    // ---- prologue: B tiles 0,1 in flight; A panel staged (nt, sequential) ----
    issueB(0, 0);
    __builtin_amdgcn_sched_barrier(0);
    issueB(1, 1);
    __builtin_amdgcn_sched_barrier(0);

    // A: wave stages rows wid*16 .. wid*16+15, one full 1KB row per instr.
    {
        const float* xw = xb + (n0 + wid * 16) * 256 + l * 4;
        const int csw = l >> 1;
        const int sub = (l & 1) * 8;
        f32x4 xa[8];
#pragma unroll
        for (int s2 = 0; s2 < 2; ++s2) {
#pragma unroll
            for (int j = 0; j < 8; ++j)
                xa[j] = __builtin_nontemporal_load(
                    (const f32x4*)(xw + (s2 * 8 + j) * 256));
            __builtin_amdgcn_sched_barrier(0);
#pragma unroll
            for (int j = 0; j < 8; ++j) {
                const int r = wid * 16 + s2 * 8 + j;
                u32x2 p;
                p.x = pk2(xa[j].x, xa[j].y);
                p.y = pk2(xa[j].z, xa[j].w);
                *(u32x2*)((char*)lds + r * 512 + ((csw ^ (r & 31)) << 4) + sub) = p;
            }
        }
    }

    flushB(0, 0);
    issueB(2, 0);
    __builtin_amdgcn_sched_barrier(0);
    asm volatile("s_waitcnt lgkmcnt(0)" ::: "memory");
    __builtin_amdgcn_sched_barrier(0);
    __builtin_amdgcn_s_barrier();

    f32x4 acc[2][8];
#pragma unroll
    for (int m = 0; m < 2; ++m)
#pragma unroll
        for (int n = 0; n < 8; ++n)
            acc[m][n] = (f32x4){0.f, 0.f, 0.f, 0.f};

    // ---- K loop: 8 rounds (R11 skeleton) ----
#pragma unroll
    for (int t = 0; t < 8; ++t) {
        const char* bbuf = (const char*)lds + B_LDS + (t & 1) * 16384;

        u32x4 af[2];
#pragma unroll
        for (int m = 0; m < 2; ++m)
            af[m] = *(const u32x4*)((const char*)lds + aRow[m]
                                    + (((t * 4 + g) ^ aKey[m]) << 4));
#pragma unroll
        for (int n = 0; n < 8; ++n) {
            const u32x4 bq = *(const u32x4*)(bbuf + bR[n]);
#pragma unroll
            for (int m = 0; m < 2; ++m)
                acc[m][n] = MFMA(af[m], bq, acc[m][n]);
        }

        if (t < 7) {
            flushB(t + 1, (t + 1) & 1);   // loads issued 2 rounds ago
            if (t < 5) {
                issueB(t + 3, (t + 1) & 1);
                __builtin_amdgcn_sched_barrier(0);   // forbid load sinking
            }
            asm volatile("s_waitcnt lgkmcnt(0)" ::: "memory");
            __builtin_amdgcn_sched_barrier(0);
            __builtin_amdgcn_s_barrier();
        }
    }

    // ---- epilogue: bias + LeakyReLU(0.2), nontemporal f32 store ----
    float biasf[8];
#pragma unroll
    for (int n = 0; n < 8; ++n)
        biasf[n] = bias[wc * 128 + n * 16 + i];

    float* ob = out + (size_t)b * (256 * 256);
#pragma unroll
    for (int m = 0; m < 2; ++m) {
#pragma unroll
        for (int r = 0; r < 4; ++r) {
            const int row = n0 + wr * 32 + m * 16 + g * 4 + r;
#pragma unroll
            for (int n = 0; n < 8; ++n) {
                float v = acc[m][n][r] + biasf[n];
                v = (v >= 0.f) ? v : 0.2f * v;
                __builtin_nontemporal_store(v, &ob[row * 256 + wc * 128 + n * 16 + i]);
            }
        }
    }
}

extern "C" void kernel_launch(void* const* d_in, const int* in_sizes, int n_in,
                              void* d_out, int out_size, void* d_ws, size_t ws_size,
                              hipStream_t stream) {
    const float* x    = (const float*)d_in[0];
    const int*   idx  = (const int*)d_in[1];
    const float* w    = (const float*)d_in[2];
    const float* bias = (const float*)d_in[3];
    float*       out  = (float*)d_out;
    (void)d_ws; (void)ws_size; (void)n_in; (void)out_size;

    const int B = in_sizes[1];          // 2048
    dim3 grid((unsigned)(B * 2)), block(512);
    hipLaunchKernelGGL(argemm_kernel, grid, block, 0, stream, x, idx, w, bias, out);
}